// Round 4
// baseline (9357.465 us; speedup 1.0000x reference)
//
#include <hip/hip_runtime.h>

// LangModelWithLSTM on MI355X (gfx950). fp32 inputs, fp32 output.
// embed-concat -> [xg GEMM -> persistent biLSTM recurrence] x2 -> MLP head.
// fp32 accuracy via bf16 MFMA with hi/lo splitting:
//   GEMMs: K-tripled streams  A={a_hi,a_lo,a_hi} x B={w_hi,w_hi,w_lo}
//   recurrence: (h_hi + h_lo) x W_hi   (W_lo term negligible)
// Cross-WG h exchange: SYSTEM-scope atomics through MALL (coherence point).
// B=16, S=512, H=512, D_IN=1024, 4H=2048, HID=1024, C=5, L=2 bidirectional.

typedef unsigned short u16;
typedef unsigned int   u32;
typedef unsigned long long u64;
typedef short s16x8 __attribute__((ext_vector_type(8)));   // MFMA A/B frag (8 bf16)
typedef float f32x4 __attribute__((ext_vector_type(4)));   // MFMA accumulator

__device__ __forceinline__ float b2f(u16 h) { return __uint_as_float(((u32)h) << 16); }
__device__ __forceinline__ u16 f2b(float x) {            // round-to-nearest-even
  u32 u = __float_as_uint(x);
  return (u16)((u + 0x7fffu + ((u >> 16) & 1u)) >> 16);
}
// A-side pair -> 3 u32 words: u16 stream {h0,l0,h0, h1,l1,h1}
__device__ __forceinline__ void packA3(float v0, float v1, u32& w0, u32& w1, u32& w2) {
  u16 h0 = f2b(v0), h1 = f2b(v1);
  u16 l0 = f2b(v0 - b2f(h0)), l1 = f2b(v1 - b2f(h1));
  w0 = (u32)h0 | ((u32)l0 << 16);
  w1 = (u32)h0 | ((u32)h1 << 16);
  w2 = (u32)l1 | ((u32)h1 << 16);
}
// B-side pair -> 3 u32 words: u16 stream {h0,h0,l0, h1,h1,l1}
__device__ __forceinline__ void packB3(float v0, float v1, u32& w0, u32& w1, u32& w2) {
  u16 h0 = f2b(v0), h1 = f2b(v1);
  u16 l0 = f2b(v0 - b2f(h0)), l1 = f2b(v1 - b2f(h1));
  w0 = (u32)h0 | ((u32)h0 << 16);
  w1 = (u32)l0 | ((u32)h1 << 16);
  w2 = (u32)h1 | ((u32)l1 << 16);
}

// ---------------------------------------------------------------- embed -> A3 triple
__global__ __launch_bounds__(256) void k_embed(const int* __restrict__ x,
    const float* __restrict__ lang, const float* __restrict__ emb, u16* __restrict__ A3) {
  const int m = blockIdx.x;                  // 8192 rows = b*512+s
  const int k = threadIdx.x * 4;             // 4 source elems
  const float* src = (k < 768) ? (lang + (size_t)m * 768 + k)
                               : (emb + (size_t)x[m] * 256 + (k - 768));
  float4 v = *(const float4*)src;
  u32 w0, w1, w2, w3, w4, w5;
  packA3(v.x, v.y, w0, w1, w2);
  packA3(v.z, v.w, w3, w4, w5);
  uint2* dst = (uint2*)(A3 + (size_t)m * 3072 + 3 * k);
  dst[0] = make_uint2(w0, w1); dst[1] = make_uint2(w2, w3); dst[2] = make_uint2(w4, w5);
}

// ---------------------------------------------------------------- weight preps
// fp32 W [rows][1024] -> triple [rows][3072]; one quad per thread.
__global__ __launch_bounds__(256) void k_prepw(const float* __restrict__ W,
    u16* __restrict__ W3, int nq) {
  const int idx = blockIdx.x * 256 + threadIdx.x;
  if (idx >= nq) return;
  const int base = idx * 4, row = base >> 10, k = base & 1023;
  float4 v = *(const float4*)(W + base);
  u32 w0, w1, w2, w3, w4, w5;
  packB3(v.x, v.y, w0, w1, w2);
  packB3(v.z, v.w, w3, w4, w5);
  uint2* dst = (uint2*)(W3 + (size_t)row * 3072 + 3 * k);
  dst[0] = make_uint2(w0, w1); dst[1] = make_uint2(w2, w3); dst[2] = make_uint2(w4, w5);
}
// Whh fp32 flat [4194304] -> hi/lo bf16 planes
__global__ __launch_bounds__(256) void k_prepwh(const float* __restrict__ W,
    u16* __restrict__ hi, u16* __restrict__ lo) {
  const int idx = blockIdx.x * 256 + threadIdx.x;   // 1,048,576 quads
  const int base = idx * 4;
  float4 v = *(const float4*)(W + base);
  u16 h[4], l[4];
  float vv[4] = {v.x, v.y, v.z, v.w};
#pragma unroll
  for (int i = 0; i < 4; ++i) { h[i] = f2b(vv[i]); l[i] = f2b(vv[i] - b2f(h[i])); }
  *(uint2*)(hi + base) = make_uint2((u32)h[0] | ((u32)h[1] << 16), (u32)h[2] | ((u32)h[3] << 16));
  *(uint2*)(lo + base) = make_uint2((u32)l[0] | ((u32)l[1] << 16), (u32)l[2] | ((u32)l[3] << 16));
}
__global__ __launch_bounds__(256) void k_prepb(const float* __restrict__ bih,
    const float* __restrict__ bhh, float* __restrict__ bsum) {
  const int tid = blockIdx.x * 256 + threadIdx.x;   // 8192
  bsum[tid] = bih[tid] + bhh[tid];
}
// act fp32 [8192][1024] -> A3 triple
__global__ __launch_bounds__(256) void k_tri(const float* __restrict__ act, u16* __restrict__ A3) {
  const int idx = blockIdx.x * 256 + threadIdx.x;   // 2,097,152 quads
  const int base = idx * 4, row = base >> 10, k = base & 1023;
  float4 v = *(const float4*)(act + base);
  u32 w0, w1, w2, w3, w4, w5;
  packA3(v.x, v.y, w0, w1, w2);
  packA3(v.z, v.w, w3, w4, w5);
  uint2* dst = (uint2*)(A3 + (size_t)row * 3072 + 3 * k);
  dst[0] = make_uint2(w0, w1); dst[1] = make_uint2(w2, w3); dst[2] = make_uint2(w4, w5);
}

// ---------------------------------------------------------------- GEMM (m97 style)
// C[m][n] = sum_k A[m][k]*B[n][k] + bias[n]. 128x128 tile, BK=32, 4 waves.
// EPI=0: fp32 -> xg layout [dir=n>>11][(s*16+b)][n&2047]  (N==4096)
// EPI=1: fp32 [m][N] + leaky-relu -> act.
template <int EPI>
__global__ __launch_bounds__(256) void k_gemm(const u16* __restrict__ A,
    const u16* __restrict__ B, const float* __restrict__ bias, float* __restrict__ outp,
    int Ka, int N) {
  __shared__ u16 As[4096];   // [128][32]
  __shared__ u16 Bs[4096];
  const int tid = threadIdx.x, wave = tid >> 6, lane = tid & 63;
  const int bm0 = blockIdx.x * 128, bn0 = blockIdx.y * 128;
  const int wm = (wave & 1) * 64, wn = (wave >> 1) * 64;
  const int kq = (lane >> 4) * 8;
  f32x4 acc[4][4];
#pragma unroll
  for (int i = 0; i < 4; ++i)
#pragma unroll
    for (int j = 0; j < 4; ++j) acc[i][j] = (f32x4){0.f, 0.f, 0.f, 0.f};

  const int srow = tid >> 2, soff = (tid & 3) * 8;
  const u16* Ag  = A + (size_t)(bm0 + srow) * Ka + soff;
  const u16* Ag2 = Ag + (size_t)64 * Ka;
  const u16* Bg  = B + (size_t)(bn0 + srow) * Ka + soff;
  const u16* Bg2 = Bg + (size_t)64 * Ka;
  u16* sA = As + wave * 512;
  u16* sB = Bs + wave * 512;

  for (int k0 = 0; k0 < Ka; k0 += 32) {
    __syncthreads();
    __builtin_amdgcn_global_load_lds((const __attribute__((address_space(1))) void*)(Ag + k0),
        (__attribute__((address_space(3))) void*)sA, 16, 0, 0);
    __builtin_amdgcn_global_load_lds((const __attribute__((address_space(1))) void*)(Ag2 + k0),
        (__attribute__((address_space(3))) void*)(sA + 2048), 16, 0, 0);
    __builtin_amdgcn_global_load_lds((const __attribute__((address_space(1))) void*)(Bg + k0),
        (__attribute__((address_space(3))) void*)sB, 16, 0, 0);
    __builtin_amdgcn_global_load_lds((const __attribute__((address_space(1))) void*)(Bg2 + k0),
        (__attribute__((address_space(3))) void*)(sB + 2048), 16, 0, 0);
    __syncthreads();
    s16x8 af[4], bf[4];
#pragma unroll
    for (int mi = 0; mi < 4; ++mi) af[mi] = *(const s16x8*)(As + (wm + mi * 16 + (lane & 15)) * 32 + kq);
#pragma unroll
    for (int ni = 0; ni < 4; ++ni) bf[ni] = *(const s16x8*)(Bs + (wn + ni * 16 + (lane & 15)) * 32 + kq);
#pragma unroll
    for (int mi = 0; mi < 4; ++mi)
#pragma unroll
      for (int ni = 0; ni < 4; ++ni)
        acc[mi][ni] = __builtin_amdgcn_mfma_f32_16x16x32_bf16(af[mi], bf[ni], acc[mi][ni], 0, 0, 0);
  }

#pragma unroll
  for (int mi = 0; mi < 4; ++mi)
#pragma unroll
    for (int r = 0; r < 4; ++r) {
      const int m = bm0 + wm + mi * 16 + (lane >> 4) * 4 + r;
#pragma unroll
      for (int ni = 0; ni < 4; ++ni) {
        const int n = bn0 + wn + ni * 16 + (lane & 15);
        float v = acc[mi][ni][r] + bias[n];
        if (EPI == 0) {
          const size_t off = (size_t)(n >> 11) * 16777216u
                           + (size_t)((m & 511) * 16 + (m >> 9)) * 2048 + (n & 2047);
          outp[off] = v;
        } else {
          v = (v > 0.f) ? v : 0.01f * v;
          outp[(size_t)m * N + n] = v;
        }
      }
    }
}

// ---------------------------------------------------------------- persistent biLSTM
// 64 WGs: dir = blk>>5; each WG owns 16 hidden units (4 gates x 16 batches).
// Wave g = gate g. W_hi frags pinned in VGPRs. h exchanged as (hi|lo) u32 per
// (b,u) via a depth-4 ring of 32KB buffers, SYSTEM-scope atomics (MALL-coherent);
// per-dir 32-flag array barrier per step.
__global__ __launch_bounds__(256) void k_rec(const float* __restrict__ xg,
    const u16* __restrict__ WhiP, const int* __restrict__ lens, u16* __restrict__ Yt,
    u16* __restrict__ hbuf, u32* __restrict__ flags, int flagbase) {
  __shared__ u16 hs[16384];            // 32KB: [2 planes][16 b][512 u]
  __shared__ float gx[4][16][17];
  const int tid = threadIdx.x, wave = tid >> 6, lane = tid & 63;
  const int dir = blockIdx.x >> 5, slice = blockIdx.x & 31, ubase = slice * 16;
  const int kq = (lane >> 4) * 8;

  s16x8 bfrag[16];                     // W_hi rows g = wave*512 + ubase + (lane&15)
  {
    const u16* wr = WhiP + ((size_t)dir * 2048 + wave * 512 + ubase + (lane & 15)) * 512 + kq;
#pragma unroll
    for (int kt = 0; kt < 16; ++kt) bfrag[kt] = *(const s16x8*)(wr + kt * 32);
  }
  const int ub = tid & 15, bb = tid >> 4;
  const int len_b = lens[bb];
  float c_st = 0.f, h_st = 0.f;
  const int bq = (lane >> 4) * 4;
  const int gcol = wave * 512 + ubase + (lane & 15);
  const float* xgp = xg + (size_t)dir * 16777216u;
  u32* myflags = flags + dir * 32;

  for (int s = 0; s < 512; ++s) {
    const int t = dir ? (511 - s) : s;
    const float* xr = xgp + ((size_t)t * 16 + bq) * 2048 + gcol;
    f32x4 acc_hi;
    acc_hi[0] = xr[0]; acc_hi[1] = xr[2048]; acc_hi[2] = xr[4096]; acc_hi[3] = xr[6144];

    if (s > 0) {
      const u32 tgt = (u32)(flagbase + s);
      bool ok;
      do {                                             // 32-lane flag poll (per dir)
        u32 f = 0xffffffffu;
        if (lane < 32) f = __hip_atomic_load(&myflags[lane], __ATOMIC_RELAXED, __HIP_MEMORY_SCOPE_SYSTEM);
        unsigned long long bal = __ballot(f >= tgt);
        ok = (~bal == 0ull);
        if (!ok) __builtin_amdgcn_s_sleep(1);
      } while (!ok);
      // SYSTEM-scope coherent read of ring slot s&3; de-interleave to hi/lo planes
      const u64* src64 = (const u64*)((const char*)hbuf + (size_t)((dir << 2) | (s & 3)) * 32768);
      u32* hs32 = (u32*)hs;
#pragma unroll
      for (int c = 0; c < 16; ++c) {
        const int i = c * 256 + tid;                   // u64 index, 4096 total
        u64 w = __hip_atomic_load(&src64[i], __ATOMIC_RELAXED, __HIP_MEMORY_SCOPE_SYSTEM);
        const u32 w0 = (u32)w, w1 = (u32)(w >> 32);    // units 2i, 2i+1: (hi|lo<<16)
        hs32[i]        = (w0 & 0xffffu) | (w1 << 16);            // hi plane
        hs32[4096 + i] = (w0 >> 16) | (w1 & 0xffff0000u);        // lo plane
      }
    }
    __syncthreads();
    if (s > 0) {
      f32x4 acc_lo = (f32x4){0.f, 0.f, 0.f, 0.f};
      const u16* hhi = hs + (size_t)(lane & 15) * 512 + kq;
      const u16* hlo = hhi + 8192;
#pragma unroll
      for (int kt = 0; kt < 16; ++kt) {
        s16x8 ah = *(const s16x8*)(hhi + kt * 32);
        s16x8 al = *(const s16x8*)(hlo + kt * 32);
        acc_hi = __builtin_amdgcn_mfma_f32_16x16x32_bf16(ah, bfrag[kt], acc_hi, 0, 0, 0);
        acc_lo = __builtin_amdgcn_mfma_f32_16x16x32_bf16(al, bfrag[kt], acc_lo, 0, 0, 0);
      }
      acc_hi += acc_lo;
    }
#pragma unroll
    for (int r = 0; r < 4; ++r) gx[wave][bq + r][lane & 15] = acc_hi[r];
    __syncthreads();

    const float gi = gx[0][bb][ub], gf = gx[1][bb][ub], gg = gx[2][bb][ub], go = gx[3][bb][ub];
    const float ii = 1.f / (1.f + __expf(-gi));
    const float ff = 1.f / (1.f + __expf(-gf));
    const float g2 = 1.f - 2.f / (__expf(2.f * gg) + 1.f);   // tanh
    const float oo = 1.f / (1.f + __expf(-go));
    const float cn = ff * c_st + ii * g2;
    const float hn = oo * (1.f - 2.f / (__expf(2.f * cn) + 1.f));
    const bool mk = (t < len_b);
    c_st = mk ? cn : c_st;
    h_st = mk ? hn : h_st;

    // output: next-layer A-triple {hi,lo,hi} of y = h_new*mask
    const float yv = mk ? hn : 0.f;
    const u16 yhi = f2b(yv), ylo = f2b(yv - b2f(yhi));
    const int ug = dir * 512 + ubase + ub;
    u16* yp = Yt + (size_t)(bb * 512 + t) * 3072 + 3 * ug;
    if (ug & 1) { yp[0] = yhi; *(u32*)(yp + 1) = (u32)ylo | ((u32)yhi << 16); }
    else        { *(u32*)yp = (u32)yhi | ((u32)ylo << 16); yp[2] = yhi; }

    if (s < 511) {                       // publish carried h to ring slot (s+1)&3
      const u16 shi = f2b(h_st);
      const u16 slo = f2b(h_st - b2f(shi));
      u32* hb32 = (u32*)((char*)hbuf + (size_t)((dir << 2) | ((s + 1) & 3)) * 32768);
      __hip_atomic_store(&hb32[bb * 512 + ubase + ub], (u32)shi | ((u32)slo << 16),
                         __ATOMIC_RELAXED, __HIP_MEMORY_SCOPE_SYSTEM);
    }
    __syncthreads();                     // every wave drains vmcnt(0) before barrier
    if (tid == 0)
      __hip_atomic_store(&myflags[slice], (u32)(flagbase + s + 1),
                         __ATOMIC_RELEASE, __HIP_MEMORY_SCOPE_SYSTEM);
  }
}

// ---------------------------------------------------------------- head: out = a2 @ W3^T + b3
__global__ __launch_bounds__(256) void k_head(const float* __restrict__ a2,
    const float* __restrict__ W3, const float* __restrict__ b3, float* __restrict__ out) {
  const int m = (blockIdx.x * 256 + threadIdx.x) >> 6;   // wave per row
  const int lane = threadIdx.x & 63;
  const float* row = a2 + (size_t)m * 1024;
  float s[5] = {0.f, 0.f, 0.f, 0.f, 0.f};
  for (int j = lane; j < 1024; j += 64) {
    const float v = row[j];
#pragma unroll
    for (int c = 0; c < 5; ++c) s[c] += v * W3[c * 1024 + j];
  }
#pragma unroll
  for (int c = 0; c < 5; ++c)
    for (int off = 32; off > 0; off >>= 1) s[c] += __shfl_down(s[c], off, 64);
  if (lane == 0)
#pragma unroll
    for (int c = 0; c < 5; ++c) out[(size_t)m * 5 + c] = s[c] + b3[c];   // fp32 output
}

// ---------------------------------------------------------------- launch
extern "C" void kernel_launch(void* const* d_in, const int* in_sizes, int n_in,
                              void* d_out, int out_size, void* d_ws, size_t ws_size,
                              hipStream_t stream) {
  const int*   x    = (const int*)d_in[0];
  const int*   lens = (const int*)d_in[1];
  const float* lang = (const float*)d_in[2];
  const float* emb  = (const float*)d_in[3];
  const float* Wih  = (const float*)d_in[4];   // [2][2][2048][1024]
  const float* Whh  = (const float*)d_in[5];   // [2][2][2048][512]
  const float* bih  = (const float*)d_in[6];
  const float* bhh  = (const float*)d_in[7];
  const float* W1   = (const float*)d_in[8];
  const float* b1   = (const float*)d_in[9];
  const float* W2   = (const float*)d_in[10];
  const float* b2   = (const float*)d_in[11];
  const float* W3   = (const float*)d_in[12];
  const float* b3   = (const float*)d_in[13];
  float* out = (float*)d_out;
  char* ws = (char*)d_ws;

  // workspace (~223 MiB). act overlays xg (xg dead after k_rec layer 1).
  float* xg     = (float*)(ws + 0);             // [2][8192][2048] f32  134,217,728
  float* act    = (float*)(ws + 0);             //  [8192][1024] f32 overlay
  u16*   A3     = (u16*)(ws + 134217728);       //  [8192][3072] u16     50,331,648
  u16*   wb3    = (u16*)(ws + 184549376);       //  [4096][3072] u16     25,165,824
  u16*   whh_hi = (u16*)(ws + 209715200);       //  [2][2][2048][512]     8,388,608
  u16*   whh_lo = (u16*)(ws + 218103808);       //                        8,388,608
  u16*   w3b    = (u16*)(ws + 226492416);       //  [1024][3072] u16      6,291,456
  u16*   hbuf   = (u16*)(ws + 232783872);       //  [2][4][32KB] ring       262,144
  float* bsum   = (float*)(ws + 233046016);     //  [2][2][2048]             32,768
  u32*   flags  = (u32*)(ws + 233078784);       //  [2][32]                     256

  hipMemsetAsync(flags, 0, 256, stream);
  k_prepb<<<32, 256, 0, stream>>>(bih, bhh, bsum);
  k_prepwh<<<4096, 256, 0, stream>>>(Whh, whh_hi, whh_lo);
  k_embed<<<8192, 256, 0, stream>>>(x, lang, emb, A3);

  // layer 0
  k_prepw<<<4096, 256, 0, stream>>>(Wih, wb3, 1048576);
  k_gemm<0><<<dim3(64, 32), 256, 0, stream>>>(A3, wb3, bsum, xg, 3072, 4096);
  k_rec<<<64, 256, 0, stream>>>(xg, whh_hi, lens, A3, hbuf, flags, 0);
  // layer 1
  k_prepw<<<4096, 256, 0, stream>>>(Wih + 4194304, wb3, 1048576);
  k_gemm<0><<<dim3(64, 32), 256, 0, stream>>>(A3, wb3, bsum + 4096, xg, 3072, 4096);
  k_rec<<<64, 256, 0, stream>>>(xg, whh_hi + 2097152, lens, A3, hbuf, flags, 512);
  // head
  k_prepw<<<1024, 256, 0, stream>>>(W1, w3b, 262144);
  k_gemm<1><<<dim3(64, 8), 256, 0, stream>>>(A3, w3b, b1, act, 3072, 1024);
  k_tri<<<8192, 256, 0, stream>>>(act, A3);
  k_prepw<<<1024, 256, 0, stream>>>(W2, w3b, 262144);
  k_gemm<1><<<dim3(64, 8), 256, 0, stream>>>(A3, w3b, b2, act, 3072, 1024);
  k_head<<<2048, 256, 0, stream>>>(act, W3, b3, out);
}

// Round 5
// 5584.755 us; speedup vs baseline: 1.6755x; 1.6755x over previous
//
#include <hip/hip_runtime.h>

// LangModelWithLSTM on MI355X (gfx950). fp32 inputs, fp32 output.
// embed-concat -> [xg GEMM -> persistent biLSTM recurrence] x2 -> MLP head.
// fp32 accuracy via bf16 MFMA with hi/lo splitting:
//   GEMMs: K-tripled streams  A={a_hi,a_lo,a_hi} x B={w_hi,w_hi,w_lo}
//   recurrence: (h_hi + h_lo) x W_hi   (W_lo term negligible)
// Cross-WG h exchange: AGENT-scope atomics through MALL (coherence point).
// B=16, S=512, H=512, D_IN=1024, 4H=2048, HID=1024, C=5, L=2 bidirectional.

typedef unsigned short u16;
typedef unsigned int   u32;
typedef unsigned long long u64;
typedef short s16x8 __attribute__((ext_vector_type(8)));   // MFMA A/B frag (8 bf16)
typedef float f32x4 __attribute__((ext_vector_type(4)));   // MFMA accumulator

__device__ __forceinline__ float b2f(u16 h) { return __uint_as_float(((u32)h) << 16); }
__device__ __forceinline__ u16 f2b(float x) {            // round-to-nearest-even
  u32 u = __float_as_uint(x);
  return (u16)((u + 0x7fffu + ((u >> 16) & 1u)) >> 16);
}
// A-side pair -> 3 u32 words: u16 stream {h0,l0,h0, h1,l1,h1}
__device__ __forceinline__ void packA3(float v0, float v1, u32& w0, u32& w1, u32& w2) {
  u16 h0 = f2b(v0), h1 = f2b(v1);
  u16 l0 = f2b(v0 - b2f(h0)), l1 = f2b(v1 - b2f(h1));
  w0 = (u32)h0 | ((u32)l0 << 16);
  w1 = (u32)h0 | ((u32)h1 << 16);
  w2 = (u32)l1 | ((u32)h1 << 16);
}
// B-side pair -> 3 u32 words: u16 stream {h0,h0,l0, h1,h1,l1}
__device__ __forceinline__ void packB3(float v0, float v1, u32& w0, u32& w1, u32& w2) {
  u16 h0 = f2b(v0), h1 = f2b(v1);
  u16 l0 = f2b(v0 - b2f(h0)), l1 = f2b(v1 - b2f(h1));
  w0 = (u32)h0 | ((u32)h0 << 16);
  w1 = (u32)l0 | ((u32)h1 << 16);
  w2 = (u32)h1 | ((u32)l1 << 16);
}

// ---------------------------------------------------------------- embed -> A3 triple
__global__ __launch_bounds__(256) void k_embed(const int* __restrict__ x,
    const float* __restrict__ lang, const float* __restrict__ emb, u16* __restrict__ A3) {
  const int m = blockIdx.x;                  // 8192 rows = b*512+s
  const int k = threadIdx.x * 4;             // 4 source elems
  const float* src = (k < 768) ? (lang + (size_t)m * 768 + k)
                               : (emb + (size_t)x[m] * 256 + (k - 768));
  float4 v = *(const float4*)src;
  u32 w0, w1, w2, w3, w4, w5;
  packA3(v.x, v.y, w0, w1, w2);
  packA3(v.z, v.w, w3, w4, w5);
  uint2* dst = (uint2*)(A3 + (size_t)m * 3072 + 3 * k);
  dst[0] = make_uint2(w0, w1); dst[1] = make_uint2(w2, w3); dst[2] = make_uint2(w4, w5);
}

// ---------------------------------------------------------------- weight preps
// fp32 W [rows][1024] -> triple [rows][3072]; one quad per thread.
__global__ __launch_bounds__(256) void k_prepw(const float* __restrict__ W,
    u16* __restrict__ W3, int nq) {
  const int idx = blockIdx.x * 256 + threadIdx.x;
  if (idx >= nq) return;
  const int base = idx * 4, row = base >> 10, k = base & 1023;
  float4 v = *(const float4*)(W + base);
  u32 w0, w1, w2, w3, w4, w5;
  packB3(v.x, v.y, w0, w1, w2);
  packB3(v.z, v.w, w3, w4, w5);
  uint2* dst = (uint2*)(W3 + (size_t)row * 3072 + 3 * k);
  dst[0] = make_uint2(w0, w1); dst[1] = make_uint2(w2, w3); dst[2] = make_uint2(w4, w5);
}
// Whh fp32 flat [4194304] -> hi bf16 plane (lo plane dropped in recurrence)
__global__ __launch_bounds__(256) void k_prepwh(const float* __restrict__ W,
    u16* __restrict__ hi) {
  const int idx = blockIdx.x * 256 + threadIdx.x;   // 1,048,576 quads
  const int base = idx * 4;
  float4 v = *(const float4*)(W + base);
  float vv[4] = {v.x, v.y, v.z, v.w};
  u16 h[4];
#pragma unroll
  for (int i = 0; i < 4; ++i) h[i] = f2b(vv[i]);
  *(uint2*)(hi + base) = make_uint2((u32)h[0] | ((u32)h[1] << 16), (u32)h[2] | ((u32)h[3] << 16));
}
__global__ __launch_bounds__(256) void k_prepb(const float* __restrict__ bih,
    const float* __restrict__ bhh, float* __restrict__ bsum) {
  const int tid = blockIdx.x * 256 + threadIdx.x;   // 8192
  bsum[tid] = bih[tid] + bhh[tid];
}
// act fp32 [8192][1024] -> A3 triple
__global__ __launch_bounds__(256) void k_tri(const float* __restrict__ act, u16* __restrict__ A3) {
  const int idx = blockIdx.x * 256 + threadIdx.x;   // 2,097,152 quads
  const int base = idx * 4, row = base >> 10, k = base & 1023;
  float4 v = *(const float4*)(act + base);
  u32 w0, w1, w2, w3, w4, w5;
  packA3(v.x, v.y, w0, w1, w2);
  packA3(v.z, v.w, w3, w4, w5);
  uint2* dst = (uint2*)(A3 + (size_t)row * 3072 + 3 * k);
  dst[0] = make_uint2(w0, w1); dst[1] = make_uint2(w2, w3); dst[2] = make_uint2(w4, w5);
}

// ---------------------------------------------------------------- GEMM (m97 style)
// C[m][n] = sum_k A[m][k]*B[n][k] + bias[n]. 128x128 tile, BK=32, 4 waves.
// EPI=0: fp32 -> xg layout [dir=n>>11][(s*16+b)][n&2047]  (N==4096)
// EPI=1: fp32 [m][N] + leaky-relu -> act.
template <int EPI>
__global__ __launch_bounds__(256) void k_gemm(const u16* __restrict__ A,
    const u16* __restrict__ B, const float* __restrict__ bias, float* __restrict__ outp,
    int Ka, int N) {
  __shared__ u16 As[4096];   // [128][32]
  __shared__ u16 Bs[4096];
  const int tid = threadIdx.x, wave = tid >> 6, lane = tid & 63;
  const int bm0 = blockIdx.x * 128, bn0 = blockIdx.y * 128;
  const int wm = (wave & 1) * 64, wn = (wave >> 1) * 64;
  const int kq = (lane >> 4) * 8;
  f32x4 acc[4][4];
#pragma unroll
  for (int i = 0; i < 4; ++i)
#pragma unroll
    for (int j = 0; j < 4; ++j) acc[i][j] = (f32x4){0.f, 0.f, 0.f, 0.f};

  const int srow = tid >> 2, soff = (tid & 3) * 8;
  const u16* Ag  = A + (size_t)(bm0 + srow) * Ka + soff;
  const u16* Ag2 = Ag + (size_t)64 * Ka;
  const u16* Bg  = B + (size_t)(bn0 + srow) * Ka + soff;
  const u16* Bg2 = Bg + (size_t)64 * Ka;
  u16* sA = As + wave * 512;
  u16* sB = Bs + wave * 512;

  for (int k0 = 0; k0 < Ka; k0 += 32) {
    __syncthreads();
    __builtin_amdgcn_global_load_lds((const __attribute__((address_space(1))) void*)(Ag + k0),
        (__attribute__((address_space(3))) void*)sA, 16, 0, 0);
    __builtin_amdgcn_global_load_lds((const __attribute__((address_space(1))) void*)(Ag2 + k0),
        (__attribute__((address_space(3))) void*)(sA + 2048), 16, 0, 0);
    __builtin_amdgcn_global_load_lds((const __attribute__((address_space(1))) void*)(Bg + k0),
        (__attribute__((address_space(3))) void*)sB, 16, 0, 0);
    __builtin_amdgcn_global_load_lds((const __attribute__((address_space(1))) void*)(Bg2 + k0),
        (__attribute__((address_space(3))) void*)(sB + 2048), 16, 0, 0);
    __syncthreads();
    s16x8 af[4], bf[4];
#pragma unroll
    for (int mi = 0; mi < 4; ++mi) af[mi] = *(const s16x8*)(As + (wm + mi * 16 + (lane & 15)) * 32 + kq);
#pragma unroll
    for (int ni = 0; ni < 4; ++ni) bf[ni] = *(const s16x8*)(Bs + (wn + ni * 16 + (lane & 15)) * 32 + kq);
#pragma unroll
    for (int mi = 0; mi < 4; ++mi)
#pragma unroll
      for (int ni = 0; ni < 4; ++ni)
        acc[mi][ni] = __builtin_amdgcn_mfma_f32_16x16x32_bf16(af[mi], bf[ni], acc[mi][ni], 0, 0, 0);
  }

#pragma unroll
  for (int mi = 0; mi < 4; ++mi)
#pragma unroll
    for (int r = 0; r < 4; ++r) {
      const int m = bm0 + wm + mi * 16 + (lane >> 4) * 4 + r;
#pragma unroll
      for (int ni = 0; ni < 4; ++ni) {
        const int n = bn0 + wn + ni * 16 + (lane & 15);
        float v = acc[mi][ni][r] + bias[n];
        if (EPI == 0) {
          const size_t off = (size_t)(n >> 11) * 16777216u
                           + (size_t)((m & 511) * 16 + (m >> 9)) * 2048 + (n & 2047);
          outp[off] = v;
        } else {
          v = (v > 0.f) ? v : 0.01f * v;
          outp[(size_t)m * N + n] = v;
        }
      }
    }
}

// ---------------------------------------------------------------- persistent biLSTM
// 32 WGs: dir = blk>>4; each WG owns 32 hidden units (4 gates x 16 batches).
// Wave g = gate g, 2 column-tiles of 16 units. W_hi frags pinned in VGPRs
// (launch_bounds(256,1) -> no occupancy cap). h exchanged as (hi|lo) u32 per
// (b,u) via a depth-4 ring of 32KB buffers, AGENT-scope atomics (MALL);
// per-dir 16-flag array (one 64B line) per step. LDS h rows padded to 520 u16
// (1040B stride -> 2-way bank aliasing = free) to kill the 16-way conflicts.
__global__ __launch_bounds__(256, 1) void k_rec(const float* __restrict__ xg,
    const u16* __restrict__ WhiP, const int* __restrict__ lens, u16* __restrict__ Yt,
    u16* __restrict__ hbuf, u32* __restrict__ flags, int flagbase) {
  __shared__ u16 hs[2 * 16 * 520];     // [plane hi/lo][batch][512+8 pad]
  __shared__ float gx[4][16][33];      // [gate][batch][32 units + pad]
  const int tid = threadIdx.x, wave = tid >> 6, lane = tid & 63;
  const int dir = blockIdx.x >> 4, slice = blockIdx.x & 15, ubase = slice * 32;
  const int kq = (lane >> 4) * 8;
  const int col = lane & 15;
  const int bq = (lane >> 4) * 4;

  s16x8 bfrag[2][16];                  // W_hi rows g = wave*512 + ubase + j*16 + col
#pragma unroll
  for (int j = 0; j < 2; ++j) {
    const u16* wr = WhiP + ((size_t)dir * 2048 + wave * 512 + ubase + j * 16 + col) * 512 + kq;
#pragma unroll
    for (int kt = 0; kt < 16; ++kt) bfrag[j][kt] = *(const s16x8*)(wr + kt * 32);
  }
  const int pp = tid & 15, bb = tid >> 4;   // pointwise: units 2pp,2pp+1, batch bb
  const int len_b = lens[bb];
  float c0 = 0.f, h0v = 0.f, c1 = 0.f, h1v = 0.f;
  const float* xgp = xg + (size_t)dir * 16777216u;
  u32* myflags = flags + dir * 16;

  for (int s = 0; s < 512; ++s) {
    const int t = dir ? (511 - s) : s;
    // prefetch this step's xg (in flight during poll); acc rows b=bq+r, cols j*16+col
    const float* xr = xgp + ((size_t)t * 16 + bq) * 2048 + wave * 512 + ubase + col;
    f32x4 a0, a1;
    a0[0] = xr[0];  a0[1] = xr[2048]; a0[2] = xr[4096]; a0[3] = xr[6144];
    a1[0] = xr[16]; a1[1] = xr[2064]; a1[2] = xr[4112]; a1[3] = xr[6160];

    if (s > 0) {
      const u32 tgt = (u32)(flagbase + s);
      bool ok;
      do {                                             // 16-flag poll: one 64B line
        u32 f = 0xffffffffu;
        if (lane < 16) f = __hip_atomic_load(&myflags[lane], __ATOMIC_RELAXED, __HIP_MEMORY_SCOPE_AGENT);
        ok = (~__ballot(f >= tgt)) == 0ull;
        if (!ok) __builtin_amdgcn_s_sleep(1);
      } while (!ok);
      // phase 1: issue all 16 coherent loads (stay in flight together)
      const u64* src = (const u64*)hbuf + (size_t)(dir * 4 + (s & 3)) * 4096;
      u64 w[16];
#pragma unroll
      for (int c = 0; c < 16; ++c)
        w[c] = __hip_atomic_load(&src[c * 256 + tid], __ATOMIC_RELAXED, __HIP_MEMORY_SCOPE_AGENT);
      // phase 2: de-interleave to padded hi/lo planes (units 2tid,2tid+1 of batch c)
#pragma unroll
      for (int c = 0; c < 16; ++c) {
        const u32 w0 = (u32)w[c], w1 = (u32)(w[c] >> 32);
        *(u32*)(hs + c * 520 + 2 * tid)        = (w0 & 0xffffu) | (w1 << 16);
        *(u32*)(hs + 8320 + c * 520 + 2 * tid) = (w0 >> 16) | (w1 & 0xffff0000u);
      }
    }
    __syncthreads();
    if (s > 0) {
      f32x4 l0 = (f32x4){0.f, 0.f, 0.f, 0.f}, l1 = (f32x4){0.f, 0.f, 0.f, 0.f};
      const u16* hh = hs + col * 520 + kq;     // A row = batch = col
      const u16* hl = hh + 8320;
#pragma unroll
      for (int kt = 0; kt < 16; ++kt) {
        s16x8 ah = *(const s16x8*)(hh + kt * 32);
        s16x8 al = *(const s16x8*)(hl + kt * 32);
        a0 = __builtin_amdgcn_mfma_f32_16x16x32_bf16(ah, bfrag[0][kt], a0, 0, 0, 0);
        a1 = __builtin_amdgcn_mfma_f32_16x16x32_bf16(ah, bfrag[1][kt], a1, 0, 0, 0);
        l0 = __builtin_amdgcn_mfma_f32_16x16x32_bf16(al, bfrag[0][kt], l0, 0, 0, 0);
        l1 = __builtin_amdgcn_mfma_f32_16x16x32_bf16(al, bfrag[1][kt], l1, 0, 0, 0);
      }
      a0 += l0; a1 += l1;
    }
#pragma unroll
    for (int r = 0; r < 4; ++r) {
      gx[wave][bq + r][col] = a0[r];
      gx[wave][bq + r][16 + col] = a1[r];
    }
    __syncthreads();

    const int u0 = 2 * pp, u1 = u0 + 1;
    const float gi0 = gx[0][bb][u0], gf0 = gx[1][bb][u0], gg0 = gx[2][bb][u0], go0 = gx[3][bb][u0];
    const float gi1 = gx[0][bb][u1], gf1 = gx[1][bb][u1], gg1 = gx[2][bb][u1], go1 = gx[3][bb][u1];
    const float ii0 = 1.f / (1.f + __expf(-gi0)),  ii1 = 1.f / (1.f + __expf(-gi1));
    const float ff0 = 1.f / (1.f + __expf(-gf0)),  ff1 = 1.f / (1.f + __expf(-gf1));
    const float gz0 = 1.f - 2.f / (__expf(2.f * gg0) + 1.f);   // tanh
    const float gz1 = 1.f - 2.f / (__expf(2.f * gg1) + 1.f);
    const float oo0 = 1.f / (1.f + __expf(-go0)),  oo1 = 1.f / (1.f + __expf(-go1));
    const float cn0 = ff0 * c0 + ii0 * gz0,        cn1 = ff1 * c1 + ii1 * gz1;
    const float hn0 = oo0 * (1.f - 2.f / (__expf(2.f * cn0) + 1.f));
    const float hn1 = oo1 * (1.f - 2.f / (__expf(2.f * cn1) + 1.f));
    const bool mk = (t < len_b);
    c0 = mk ? cn0 : c0;  h0v = mk ? hn0 : h0v;
    c1 = mk ? cn1 : c1;  h1v = mk ? hn1 : h1v;

    // output: next-layer A-triple {hi,lo,hi} of y = h_new*mask (unit pair -> 12B)
    const float y0 = mk ? hn0 : 0.f, y1 = mk ? hn1 : 0.f;
    u32 w0, w1, w2;
    packA3(y0, y1, w0, w1, w2);
    const int ug = dir * 512 + ubase + u0;               // even
    u32* yp = (u32*)(Yt + (size_t)(bb * 512 + t) * 3072 + 3 * ug);
    yp[0] = w0; yp[1] = w1; yp[2] = w2;

    if (s < 511) {                       // publish carried h pair to ring slot (s+1)&3
      const u16 s0h = f2b(h0v), s0l = f2b(h0v - b2f(s0h));
      const u16 s1h = f2b(h1v), s1l = f2b(h1v - b2f(s1h));
      const u64 wv = (u64)((u32)s0h | ((u32)s0l << 16))
                   | ((u64)((u32)s1h | ((u32)s1l << 16)) << 32);
      u64* dst = (u64*)hbuf + (size_t)(dir * 4 + ((s + 1) & 3)) * 4096
               + (size_t)bb * 256 + (ubase >> 1) + pp;
      __hip_atomic_store(dst, wv, __ATOMIC_RELAXED, __HIP_MEMORY_SCOPE_AGENT);
    }
    __syncthreads();                     // all waves drain vmcnt before barrier
    if (tid == 0)
      __hip_atomic_store(&myflags[slice], (u32)(flagbase + s + 1),
                         __ATOMIC_RELEASE, __HIP_MEMORY_SCOPE_AGENT);
  }
}

// ---------------------------------------------------------------- head: out = a2 @ W3^T + b3
__global__ __launch_bounds__(256) void k_head(const float* __restrict__ a2,
    const float* __restrict__ W3, const float* __restrict__ b3, float* __restrict__ out) {
  const int m = (blockIdx.x * 256 + threadIdx.x) >> 6;   // wave per row
  const int lane = threadIdx.x & 63;
  const float* row = a2 + (size_t)m * 1024;
  float s[5] = {0.f, 0.f, 0.f, 0.f, 0.f};
  for (int j = lane; j < 1024; j += 64) {
    const float v = row[j];
#pragma unroll
    for (int c = 0; c < 5; ++c) s[c] += v * W3[c * 1024 + j];
  }
#pragma unroll
  for (int c = 0; c < 5; ++c)
    for (int off = 32; off > 0; off >>= 1) s[c] += __shfl_down(s[c], off, 64);
  if (lane == 0)
#pragma unroll
    for (int c = 0; c < 5; ++c) out[(size_t)m * 5 + c] = s[c] + b3[c];   // fp32 output
}

// ---------------------------------------------------------------- launch
extern "C" void kernel_launch(void* const* d_in, const int* in_sizes, int n_in,
                              void* d_out, int out_size, void* d_ws, size_t ws_size,
                              hipStream_t stream) {
  const int*   x    = (const int*)d_in[0];
  const int*   lens = (const int*)d_in[1];
  const float* lang = (const float*)d_in[2];
  const float* emb  = (const float*)d_in[3];
  const float* Wih  = (const float*)d_in[4];   // [2][2][2048][1024]
  const float* Whh  = (const float*)d_in[5];   // [2][2][2048][512]
  const float* bih  = (const float*)d_in[6];
  const float* bhh  = (const float*)d_in[7];
  const float* W1   = (const float*)d_in[8];
  const float* b1   = (const float*)d_in[9];
  const float* W2   = (const float*)d_in[10];
  const float* b2   = (const float*)d_in[11];
  const float* W3   = (const float*)d_in[12];
  const float* b3   = (const float*)d_in[13];
  float* out = (float*)d_out;
  char* ws = (char*)d_ws;

  // workspace (~223 MiB). act overlays xg (xg dead after k_rec layer 1).
  float* xg     = (float*)(ws + 0);             // [2][8192][2048] f32  134,217,728
  float* act    = (float*)(ws + 0);             //  [8192][1024] f32 overlay
  u16*   A3     = (u16*)(ws + 134217728);       //  [8192][3072] u16     50,331,648
  u16*   wb3    = (u16*)(ws + 184549376);       //  [4096][3072] u16     25,165,824
  u16*   whh_hi = (u16*)(ws + 209715200);       //  [2][2][2048][512]     8,388,608
  u16*   w3b    = (u16*)(ws + 226492416);       //  [1024][3072] u16      6,291,456
  u16*   hbuf   = (u16*)(ws + 232783872);       //  [2][4][32KB] ring       262,144
  float* bsum   = (float*)(ws + 233046016);     //  [2][2][2048]             32,768
  u32*   flags  = (u32*)(ws + 233078784);       //  [2][16]                     256

  hipMemsetAsync(flags, 0, 256, stream);
  k_prepb<<<32, 256, 0, stream>>>(bih, bhh, bsum);
  k_prepwh<<<4096, 256, 0, stream>>>(Whh, whh_hi);
  k_embed<<<8192, 256, 0, stream>>>(x, lang, emb, A3);

  // layer 0
  k_prepw<<<4096, 256, 0, stream>>>(Wih, wb3, 1048576);
  k_gemm<0><<<dim3(64, 32), 256, 0, stream>>>(A3, wb3, bsum, xg, 3072, 4096);
  k_rec<<<32, 256, 0, stream>>>(xg, whh_hi, lens, A3, hbuf, flags, 0);
  // layer 1
  k_prepw<<<4096, 256, 0, stream>>>(Wih + 4194304, wb3, 1048576);
  k_gemm<0><<<dim3(64, 32), 256, 0, stream>>>(A3, wb3, bsum + 4096, xg, 3072, 4096);
  k_rec<<<32, 256, 0, stream>>>(xg, whh_hi + 2097152, lens, A3, hbuf, flags, 512);
  // head
  k_prepw<<<1024, 256, 0, stream>>>(W1, w3b, 262144);
  k_gemm<1><<<dim3(64, 8), 256, 0, stream>>>(A3, w3b, b1, act, 3072, 1024);
  k_tri<<<8192, 256, 0, stream>>>(act, A3);
  k_prepw<<<1024, 256, 0, stream>>>(W2, w3b, 262144);
  k_gemm<1><<<dim3(64, 8), 256, 0, stream>>>(A3, w3b, b2, act, 3072, 1024);
  k_head<<<2048, 256, 0, stream>>>(act, W3, b3, out);
}